// Round 10
// baseline (235.941 us; speedup 1.0000x reference)
//
#include <hip/hip_runtime.h>

typedef unsigned short u16;
typedef unsigned int   u32;
typedef float  f32x4  __attribute__((ext_vector_type(4)));
typedef float  fltx4  __attribute__((ext_vector_type(4)));
typedef float  f32x2  __attribute__((ext_vector_type(2)));
typedef short  bf16x8 __attribute__((ext_vector_type(8)));  // 8 bf16 bits in 4 VGPRs
typedef u32    u32x4  __attribute__((ext_vector_type(4)));
typedef u32    u32x2  __attribute__((ext_vector_type(2)));

#define CDIM 256
#define NPIX 4096
// (1/sqrt(256)) * log2(e): fold attention scale + exp2 conversion into wq3
#define QSCALE 0.09016843736f

__device__ __forceinline__ u16 f2bf(float f) {
  u32 u = __builtin_bit_cast(u32, f);
  u += 0x7fffu + ((u >> 16) & 1u);          // RNE truncate to bf16
  return (u16)(u >> 16);
}
__device__ __forceinline__ float bf2f(u16 h) {
  return __builtin_bit_cast(float, (u32)h << 16);
}

// raw v_exp_f32 (2^x, ~1 ULP). Identical to exp2f for |x| < 126; skips OCML guard.
#if __has_builtin(__builtin_amdgcn_exp2f)
#define FEXP2 __builtin_amdgcn_exp2f
#else
#define FEXP2 exp2f
#endif

#define LO2(v) __builtin_shufflevector(v, v, 0, 1)
#define HI2(v) __builtin_shufflevector(v, v, 2, 3)

union U8 { bf16x8 v; u16 u[8]; u32 w[4]; };

// async 16B/lane global->LDS DMA; lds_base is wave-uniform, HW adds lane*16
__device__ __forceinline__ void llds16(u16* lds_base, const u16* gsrc) {
  __builtin_amdgcn_global_load_lds(
      (const __attribute__((address_space(1))) unsigned int*)gsrc,
      (__attribute__((address_space(3))) unsigned int*)lds_base, 16, 0, 0);
}

// ------------------------------------- gn_stats + prep fused (one dispatch fewer)
// blocks 0-255: groupnorm stats. 256-259: wkvV/wout -> bf16. 260-263: wq3 partials.
__global__ __launch_bounds__(1024) void gn_stats_prep(
    const float* __restrict__ x, const float* __restrict__ wkv,
    const float* __restrict__ wout, const float* __restrict__ wq,
    float* __restrict__ stats, u16* __restrict__ w16, float* __restrict__ wq3p) {
  const int bid = blockIdx.x, tid = threadIdx.x;
  if (bid < 256) {
    const float* base = x + (long)bid * 32768;   // b*32+g ; 8 ch x 4096 contiguous
    float s = 0.f, s2 = 0.f;
    for (int i = tid; i < 8192; i += 1024) {
      fltx4 v = ((const fltx4*)base)[i];
      s  += v[0] + v[1] + v[2] + v[3];
      s2 += v[0]*v[0] + v[1]*v[1] + v[2]*v[2] + v[3]*v[3];
    }
    for (int off = 1; off < 64; off <<= 1) {
      s  += __shfl_xor(s, off);
      s2 += __shfl_xor(s2, off);
    }
    __shared__ float red[32];
    int w = tid >> 6;                            // 16 waves
    if ((tid & 63) == 0) { red[w] = s; red[16 + w] = s2; }
    __syncthreads();
    if (tid < 16) {
      s  = red[tid];
      s2 = red[16 + tid];
      for (int off = 1; off < 16; off <<= 1) {
        s  += __shfl_xor(s, off);
        s2 += __shfl_xor(s2, off);
      }
      if (tid == 0) {
        float mean = s * (1.f / 32768.f);
        float var  = s2 * (1.f / 32768.f) - mean * mean;
        stats[bid * 2]     = mean;
        stats[bid * 2 + 1] = rsqrtf(var + 1e-5f);
      }
    }
    return;
  }
  const int blk = bid - 256;
  if (blk < 4) {
    const float* s = (blk < 2 ? wkv + 65536 : wout) + (blk & 1) * 32768;
    u16* d = w16 + (blk >> 1) * 65536 + (blk & 1) * 32768;
    for (int i = tid * 4; i < 32768; i += 4096) {
      fltx4 v = *(const fltx4*)(s + i);
      u32x2 o;
      o[0] = (u32)f2bf(v[0]) | ((u32)f2bf(v[1]) << 16);
      o[1] = (u32)f2bf(v[2]) | ((u32)f2bf(v[3]) << 16);
      *(u32x2*)(d + i) = o;
    }
  } else if (tid < 256) {
    const int p = blk - 4, c = tid;
    float a0 = 0.f, a1 = 0.f, a2 = 0.f;
    for (int o = p * 64; o < p * 64 + 64; ++o) {
      float kv = wkv[o * 256 + c];
      a0 += wq[o * 3 + 0] * kv;
      a1 += wq[o * 3 + 1] * kv;
      a2 += wq[o * 3 + 2] * kv;
    }
    float* dst = wq3p + (p * 256 + c) * 4;
    dst[0] = a0 * QSCALE; dst[1] = a1 * QSCALE; dst[2] = a2 * QSCALE; dst[3] = 0.f;
  }
}

// --------------------- FUSED: groupnorm-apply + K3 + V-GEMM (normT eliminated)
#define TSTR 264
__global__ __launch_bounds__(256) void gn_fused(const float* __restrict__ x,
                                                const float* __restrict__ stats,
                                                const float* __restrict__ gamma,
                                                const float* __restrict__ beta,
                                                const float* __restrict__ wq3p,
                                                const u16* __restrict__ w16v,
                                                u16* __restrict__ Vv,
                                                float* __restrict__ K3x,
                                                float* __restrict__ K3y,
                                                float* __restrict__ K3z) {
  __shared__ u16 tile[64 * TSTR];            // ~33.8 KB, [n][c]
  __shared__ float wl4[256 * 4];             // combined wq3, 4 KB
  __shared__ float part[4][64][4];           // c-quarter partial K3, 4 KB
  const int tid = threadIdx.x;
  const int b = blockIdx.y, nb = blockIdx.x * 64;
  const int nIn = tid & 63, c4 = tid >> 6;   // c4 = wave
  const int lane = tid & 63;
  const int m = lane & 15, quad = lane >> 4;
  {
    const f32x4* wp = (const f32x4*)wq3p;
    *(f32x4*)&wl4[tid * 4] = wp[tid] + wp[256 + tid] + wp[512 + tid] + wp[768 + tid];
  }
  const float* xb = x + (long)b * (CDIM * NPIX);
  // ---- phase 1: normalize 64 c-rows (this wave's quarter) for column nIn
  #pragma unroll
  for (int p8 = 0; p8 < 8; ++p8) {
    U8 pk;
    #pragma unroll
    for (int e = 0; e < 8; ++e) {
      int c = c4 * 64 + p8 * 8 + e;
      int g = c >> 3;
      float mean = stats[(b * 32 + g) * 2];
      float rstd = stats[(b * 32 + g) * 2 + 1];
      float v = xb[(long)c * NPIX + nb + nIn];
      pk.u[e] = f2bf((v - mean) * rstd * gamma[c] + beta[c]);
    }
    *(bf16x8*)&tile[nIn * TSTR + c4 * 64 + p8 * 8] = pk.v;
  }
  __syncthreads();
  // ---- phase 2: K3 partial, vectorized row reads
  {
    float a0 = 0.f, a1 = 0.f, a2 = 0.f;
    #pragma unroll
    for (int p8 = 0; p8 < 8; ++p8) {
      U8 v; v.v = *(const bf16x8*)&tile[nIn * TSTR + c4 * 64 + p8 * 8];
      #pragma unroll
      for (int e = 0; e < 8; ++e) {
        int c = c4 * 64 + p8 * 8 + e;
        float f = bf2f(v.u[e]);
        const f32x4 wv = *(const f32x4*)&wl4[c * 4];
        a0 += f * wv[0]; a1 += f * wv[1]; a2 += f * wv[2];
      }
    }
    part[c4][nIn][0] = a0; part[c4][nIn][1] = a1; part[c4][nIn][2] = a2;
  }
  __syncthreads();
  if (c4 == 0) {
    float s0 = part[0][nIn][0] + part[1][nIn][0] + part[2][nIn][0] + part[3][nIn][0];
    float s1 = part[0][nIn][1] + part[1][nIn][1] + part[2][nIn][1] + part[3][nIn][1];
    float s2 = part[0][nIn][2] + part[1][nIn][2] + part[2][nIn][2] + part[3][nIn][2];
    long idx = (long)b * NPIX + nb + nIn;
    K3x[idx] = s0; K3y[idx] = s1; K3z[idx] = s2;
  }
  // ---- phase 3: V-GEMM. wave c4 owns o-range [c4*64, c4*64+64).
  f32x4 acc[4][4] = {};
  #pragma unroll
  for (int ks = 0; ks < 8; ++ks) {
    const int kb = ks * 32;
    bf16x8 av[4], bv[4];
    #pragma unroll
    for (int i = 0; i < 4; ++i)
      av[i] = *(const bf16x8*)&w16v[(c4 * 64 + i * 16 + m) * 256 + kb + quad * 8];
    #pragma unroll
    for (int i = 0; i < 4; ++i)
      bv[i] = *(const bf16x8*)&tile[(i * 16 + m) * TSTR + kb + quad * 8];
    #pragma unroll
    for (int mi = 0; mi < 4; ++mi)
      #pragma unroll
      for (int ni = 0; ni < 4; ++ni)
        acc[mi][ni] = __builtin_amdgcn_mfma_f32_16x16x32_bf16(av[mi], bv[ni], acc[mi][ni], 0, 0, 0);
  }
  u16* Vb = Vv + (long)b * (CDIM * NPIX);
  #pragma unroll
  for (int mi = 0; mi < 4; ++mi)
    #pragma unroll
    for (int r = 0; r < 4; ++r) {
      int o = c4 * 64 + mi * 16 + quad * 4 + r;
      #pragma unroll
      for (int ni = 0; ni < 4; ++ni)
        Vb[(long)o * NPIX + nb + ni * 16 + m] = f2bf(acc[mi][ni][r]);
    }
}

// ------------------------------------------------- final GEMM: 64x128 tile, 4 blk/CU
// out[o][n] = sum_c wout16[o][c] * ((Op0+Op1)[n][c] * inv[n]) + bias[o] + resid[o][n]
__global__ __launch_bounds__(256, 4) void gemm_out(
    const u16* __restrict__ Ap, const u16* __restrict__ B0,
    const u16* __restrict__ B1, const float* __restrict__ ls,
    float* __restrict__ out, const float* __restrict__ bias,
    const float* __restrict__ resid) {
  __shared__ u16 Als[64 * 72];               // 9.2 KB
  __shared__ u16 Bls[128 * 72];              // 18.4 KB
  __shared__ float invB[128];
  const int tid = threadIdx.x;
  const int lane = tid & 63;
  const int m = lane & 15, quad = lane >> 4;
  const int wid = tid >> 6;
  const int wm = wid & 1, wn = wid >> 1;
  const int m0 = blockIdx.x * 64, n0 = blockIdx.y * 128;
  const int bz = blockIdx.z;
  const long S = (long)NPIX * CDIM;

  if (tid < 128) {
    long n = (long)bz * 4096 + n0 + tid;
    invB[tid] = 1.f / (ls[n] + ls[32768 + n]);
  }
  __syncthreads();

  f32x4 acc[2][4] = {};

  for (int ks = 0; ks < 4; ++ks) {
    const int kb = ks * 64;
    if (ks) __syncthreads();
    // A: 64 rows x 64 k = 4096 u16 -> 2 iters of 256 thr x 8
    #pragma unroll
    for (int it = 0; it < 2; ++it) {
      int idx = it * 2048 + tid * 8;
      int r = idx >> 6, c = idx & 63;
      *(u32x4*)&Als[r * 72 + c] = *(const u32x4*)(Ap + (long)(m0 + r) * CDIM + kb + c);
    }
    // B with fused split-K merge: 128 rows -> 4 iters
    {
      const u16* s0 = B0 + S * bz;
      const u16* s1 = B1 + S * bz;
      #pragma unroll
      for (int it = 0; it < 4; ++it) {
        int idx = it * 2048 + tid * 8;
        int r = idx >> 6, c = idx & 63;
        long off = (long)(n0 + r) * CDIM + kb + c;
        u32x4 A0 = *(const u32x4*)(s0 + off);
        u32x4 A1 = *(const u32x4*)(s1 + off);
        float inv = invB[r];
        u32x4 o;
        #pragma unroll
        for (int i = 0; i < 4; ++i) {
          float lo = (bf2f((u16)(A0[i] & 0xffff)) + bf2f((u16)(A1[i] & 0xffff))) * inv;
          float hi = (bf2f((u16)(A0[i] >> 16))    + bf2f((u16)(A1[i] >> 16)))    * inv;
          o[i] = (u32)f2bf(lo) | ((u32)f2bf(hi) << 16);
        }
        *(u32x4*)&Bls[r * 72 + c] = o;
      }
    }
    __syncthreads();
    #pragma unroll
    for (int s = 0; s < 2; ++s) {
      bf16x8 av[2], bv[4];
      #pragma unroll
      for (int i = 0; i < 2; ++i)
        av[i] = *(const bf16x8*)&Als[(wm * 32 + i * 16 + m) * 72 + s * 32 + quad * 8];
      #pragma unroll
      for (int i = 0; i < 4; ++i)
        bv[i] = *(const bf16x8*)&Bls[(wn * 64 + i * 16 + m) * 72 + s * 32 + quad * 8];
      #pragma unroll
      for (int mi = 0; mi < 2; ++mi)
        #pragma unroll
        for (int ni = 0; ni < 4; ++ni)
          acc[mi][ni] = __builtin_amdgcn_mfma_f32_16x16x32_bf16(av[mi], bv[ni], acc[mi][ni], 0, 0, 0);
    }
  }

  const int row0 = m0 + wm * 32;
  const int col0 = n0 + wn * 64 + m;
  float* ob = out + S * bz;
  const float* res = resid + S * bz;
  #pragma unroll
  for (int mi = 0; mi < 2; ++mi)
    #pragma unroll
    for (int r = 0; r < 4; ++r) {
      int row = row0 + mi * 16 + quad * 4 + r;
      float bs = bias[row];
      #pragma unroll
      for (int ni = 0; ni < 4; ++ni) {
        long off = (long)row * NPIX + col0 + ni * 16;
        ob[off] = acc[mi][ni][r] + bs + res[off];
      }
    }
}

// ------------------------------------------------------------------- flash attention
// R6 structure (banked 98.5us) + s_setprio(1) around the PV MFMA clusters (T5:
// 2 independent blocks/CU give wave phase diversity -> scheduler can prefer the
// MFMA-entering wave over the other block's P-VALU waves).
#define MFMA16(a, bfr, c) __builtin_amdgcn_mfma_f32_16x16x32_bf16(a, bfr, c, 0, 0, 0)

#define P_LOAD(ks, JB)                                                      \
  {                                                                         \
    const int jo_ = (JB) + (ks) * 32 + quad * 8;                            \
    kx0 = *(const fltx4*)(Kx + jo_); kx1 = *(const fltx4*)(Kx + jo_ + 4);   \
    ky0 = *(const fltx4*)(Ky + jo_); ky1 = *(const fltx4*)(Ky + jo_ + 4);   \
    kz0 = *(const fltx4*)(Kz + jo_); kz1 = *(const fltx4*)(Kz + jo_ + 4);   \
  }

#define P_EXP(PB, ks)                                                       \
  {                                                                         \
    f32x2 xc_[4] = {LO2(kx0), HI2(kx0), LO2(kx1), HI2(kx1)};                \
    f32x2 yc_[4] = {LO2(ky0), HI2(ky0), LO2(ky1), HI2(ky1)};                \
    f32x2 zc_[4] = {LO2(kz0), HI2(kz0), LO2(kz1), HI2(kz1)};                \
    _Pragma("unroll")                                                       \
    for (int qm_ = 0; qm_ < 2; ++qm_) {                                     \
      _Pragma("unroll")                                                     \
      for (int c2_ = 0; c2_ < 4; ++c2_) {                                   \
        f32x2 s_ = xc_[c2_] * y2[qm_][0] + yc_[c2_] * y2[qm_][1]            \
                 + zc_[c2_] * y2[qm_][2];                                   \
        float p0_ = FEXP2(s_[0]);                                           \
        float p1_ = FEXP2(s_[1]);                                           \
        u32 r0_ = __builtin_bit_cast(u32, p0_) + 0x8000u;                   \
        u32 r1_ = __builtin_bit_cast(u32, p1_) + 0x8000u;                   \
        PB[qm_][ks].w[c2_] = (r0_ >> 16) | (r1_ & 0xffff0000u);             \
        f32x2 pv_; pv_[0] = p0_; pv_[1] = p1_;                              \
        lsv[qm_] += pv_;                                                    \
      }                                                                     \
    }                                                                       \
  }

#define PV_GROUP(PB, CT0)                                                   \
  _Pragma("unroll")                                                         \
  for (int ct_ = (CT0); ct_ < (CT0) + 4; ++ct_) {                           \
    int c_ = ct_ * 16 + m;                                                  \
    bf16x8 a0_ = *(const bf16x8*)&Vb[c_ * 64 + (((quad)     ^ (c_ & 7)) << 3)]; \
    bf16x8 a1_ = *(const bf16x8*)&Vb[c_ * 64 + (((4 + quad) ^ (c_ & 7)) << 3)]; \
    acc[0][ct_] = MFMA16(a0_, PB[0][0].v, acc[0][ct_]);                     \
    acc[1][ct_] = MFMA16(a0_, PB[1][0].v, acc[1][ct_]);                     \
    acc[0][ct_] = MFMA16(a1_, PB[0][1].v, acc[0][ct_]);                     \
    acc[1][ct_] = MFMA16(a1_, PB[1][1].v, acc[1][ct_]);                     \
  }

__global__ __launch_bounds__(256, 2) void attn_kernel(
    const float* __restrict__ quary,
    const float* __restrict__ K3x, const float* __restrict__ K3y,
    const float* __restrict__ K3z,
    const u16* __restrict__ V, u16* __restrict__ Op0, u16* __restrict__ Op1,
    float* __restrict__ lsum) {
  __shared__ u16 VLS[2][256 * 64];   // 2 x 32 KB; row c (256) x 64 keys, chunk ^= (c&7)
  const int lane = threadIdx.x & 63, w = threadIdx.x >> 6;   // w in [0,4)
  const int m = lane & 15, quad = lane >> 4;
  const int b = blockIdx.z, half = blockIdx.y;
  const int qb = blockIdx.x * 128 + w * 32;                  // 32 q per wave

  f32x2 y2[2][3];
  #pragma unroll
  for (int qm = 0; qm < 2; ++qm) {
    int n = qb + qm * 16 + m;
    float q0 = quary[b * 12288 + n];
    float q1 = quary[b * 12288 + 4096 + n];
    float q2 = quary[b * 12288 + 8192 + n];
    y2[qm][0][0] = q0; y2[qm][0][1] = q0;
    y2[qm][1][0] = q1; y2[qm][1][1] = q1;
    y2[qm][2][0] = q2; y2[qm][2][1] = q2;
  }

  const float* Kx = K3x + (long)b * NPIX + half * 2048;
  const float* Ky = K3y + (long)b * NPIX + half * 2048;
  const float* Kz = K3z + (long)b * NPIX + half * 2048;
  const u16* VG = V + (long)b * CDIM * NPIX + half * 2048;

  int srcV[8];
  #pragma unroll
  for (int i = 0; i < 8; ++i) {
    int c = (w * 8 + i) * 8 + (lane >> 3);
    srcV[i] = c * NPIX + (((lane & 7) ^ (c & 7)) << 3);
  }

  f32x2 lsv[2] = {};
  f32x4 acc[2][16] = {};
  U8 pbA[2][2], pbB[2][2];
  fltx4 kx0, kx1, ky0, ky1, kz0, kz1;

  #pragma unroll
  for (int i = 0; i < 8; ++i)
    llds16(VLS[0] + (w * 8 + i) * 512, VG + srcV[i]);

  P_LOAD(0, 0); P_EXP(pbA, 0);
  P_LOAD(1, 0); P_EXP(pbA, 1);

  for (int kt = 0; kt < 31; ++kt) {
    __syncthreads();
    #pragma unroll
    for (int i = 0; i < 8; ++i)
      llds16(VLS[(kt + 1) & 1] + (w * 8 + i) * 512, VG + srcV[i] + (kt + 1) * 64);
    const u16* Vb = VLS[kt & 1];
    const int JB = (kt + 1) * 64;

    P_LOAD(0, JB);
    __builtin_amdgcn_s_setprio(1);
    PV_GROUP(pbA, 0);
    PV_GROUP(pbA, 4);
    __builtin_amdgcn_s_setprio(0);
    P_EXP(pbB, 0);
    P_LOAD(1, JB);
    __builtin_amdgcn_s_setprio(1);
    PV_GROUP(pbA, 8);
    PV_GROUP(pbA, 12);
    __builtin_amdgcn_s_setprio(0);
    P_EXP(pbB, 1);

    pbA[0][0] = pbB[0][0]; pbA[0][1] = pbB[0][1];
    pbA[1][0] = pbB[1][0]; pbA[1][1] = pbB[1][1];
  }
  {
    __syncthreads();
    const u16* Vb = VLS[1];
    __builtin_amdgcn_s_setprio(1);
    PV_GROUP(pbA, 0);
    PV_GROUP(pbA, 4);
    PV_GROUP(pbA, 8);
    PV_GROUP(pbA, 12);
    __builtin_amdgcn_s_setprio(0);
  }

  u16* OpB = (half ? Op1 : Op0);
  #pragma unroll
  for (int qm = 0; qm < 2; ++qm) {
    int n = qb + qm * 16 + m;
    u16* row = OpB + ((long)b * NPIX + n) * CDIM + quad * 4;
    #pragma unroll
    for (int ct = 0; ct < 16; ++ct) {
      u32x2 o;
      o[0] = (u32)f2bf(acc[qm][ct][0]) | ((u32)f2bf(acc[qm][ct][1]) << 16);
      o[1] = (u32)f2bf(acc[qm][ct][2]) | ((u32)f2bf(acc[qm][ct][3]) << 16);
      *(u32x2*)(row + ct * 16) = o;
    }
    float ls = lsv[qm][0] + lsv[qm][1];
    ls += __shfl_xor(ls, 16);
    ls += __shfl_xor(ls, 32);
    if (lane < 16)
      lsum[(long)half * 32768 + (long)b * NPIX + n] = ls;
  }
}

// ----------------------------------------------------------------------- launch
extern "C" void kernel_launch(void* const* d_in, const int* in_sizes, int n_in,
                              void* d_out, int out_size, void* d_ws, size_t ws_size,
                              hipStream_t stream) {
  (void)in_sizes; (void)n_in; (void)out_size; (void)ws_size;
  const float* input = (const float*)d_in[0];   // (8,256,64,64)
  const float* quary = (const float*)d_in[1];   // (8,3,64,64)
  const float* gnw   = (const float*)d_in[2];   // (256)
  const float* gnb   = (const float*)d_in[3];   // (256)
  const float* wq    = (const float*)d_in[4];   // (256,3)
  const float* wkv   = (const float*)d_in[5];   // (512,256)
  const float* wout  = (const float*)d_in[6];   // (256,256)
  const float* bout  = (const float*)d_in[7];   // (256)
  float* out = (float*)d_out;

  char* ws = (char*)d_ws;
  float* stats = (float*)ws;                              // 4 KB    @0
  float* wq3p  = (float*)(ws + 4096);                     // 16 KB
  float* lsum  = (float*)(ws + 20480);                    // 256 KB (2 x 32768 f32)
  float* K3x   = (float*)(ws + 282624);                   // 128 KB plane
  float* K3y   = (float*)(ws + 413696);                   // 128 KB plane
  float* K3z   = (float*)(ws + 544768);                   // 128 KB plane
  u16* w16   = (u16*)(ws + 675840);                       // 256 KB -> ends 937984
  const long base = 937984;
  u16* Vv    = (u16*)(ws + base);                         // 16 MiB (B,C,N)
  u16* Op0   = (u16*)(ws + base + 1L * 16777216);         // 16 MiB
  u16* Op1   = (u16*)(ws + base + 2L * 16777216);         // 16 MiB

  gn_stats_prep<<<264, 1024, 0, stream>>>(input, wkv, wout, wq, stats, w16, wq3p);
  gn_fused<<<dim3(64, 8), 256, 0, stream>>>(input, stats, gnw, gnb, wq3p,
                                            w16, Vv, K3x, K3y, K3z);
  attn_kernel<<<dim3(32, 2, 8), 256, 0, stream>>>(quary, K3x, K3y, K3z, Vv, Op0, Op1, lsum);
  gemm_out<<<dim3(4, 32, 8), 256, 0, stream>>>(
      w16 + 65536, Op0, Op1, lsum, out, bout, input);
}

// Round 11
// 231.151 us; speedup vs baseline: 1.0207x; 1.0207x over previous
//
#include <hip/hip_runtime.h>

typedef unsigned short u16;
typedef unsigned int   u32;
typedef float  f32x4  __attribute__((ext_vector_type(4)));
typedef float  fltx4  __attribute__((ext_vector_type(4)));
typedef float  f32x2  __attribute__((ext_vector_type(2)));
typedef short  bf16x8 __attribute__((ext_vector_type(8)));  // 8 bf16 bits in 4 VGPRs
typedef u32    u32x4  __attribute__((ext_vector_type(4)));
typedef u32    u32x2  __attribute__((ext_vector_type(2)));

#define CDIM 256
#define NPIX 4096
// (1/sqrt(256)) * log2(e): fold attention scale + exp2 conversion into wq3
#define QSCALE 0.09016843736f

__device__ __forceinline__ u16 f2bf(float f) {
  u32 u = __builtin_bit_cast(u32, f);
  u += 0x7fffu + ((u >> 16) & 1u);          // RNE truncate to bf16
  return (u16)(u >> 16);
}
__device__ __forceinline__ float bf2f(u16 h) {
  return __builtin_bit_cast(float, (u32)h << 16);
}

// raw v_exp_f32 (2^x, ~1 ULP). Identical to exp2f for |x| < 126; skips OCML guard.
#if __has_builtin(__builtin_amdgcn_exp2f)
#define FEXP2 __builtin_amdgcn_exp2f
#else
#define FEXP2 exp2f
#endif

#define LO2(v) __builtin_shufflevector(v, v, 0, 1)
#define HI2(v) __builtin_shufflevector(v, v, 2, 3)

union U8 { bf16x8 v; u16 u[8]; u32 w[4]; };

// async 16B/lane global->LDS DMA; lds_base is wave-uniform, HW adds lane*16
__device__ __forceinline__ void llds16(u16* lds_base, const u16* gsrc) {
  __builtin_amdgcn_global_load_lds(
      (const __attribute__((address_space(1))) unsigned int*)gsrc,
      (__attribute__((address_space(3))) unsigned int*)lds_base, 16, 0, 0);
}

// ------------------------------------- gn_stats + prep fused (one dispatch fewer)
// blocks 0-255: groupnorm stats. 256-259: wkvV/wout -> bf16. 260-263: wq3 partials.
__global__ __launch_bounds__(1024) void gn_stats_prep(
    const float* __restrict__ x, const float* __restrict__ wkv,
    const float* __restrict__ wout, const float* __restrict__ wq,
    float* __restrict__ stats, u16* __restrict__ w16, float* __restrict__ wq3p) {
  const int bid = blockIdx.x, tid = threadIdx.x;
  if (bid < 256) {
    const float* base = x + (long)bid * 32768;   // b*32+g ; 8 ch x 4096 contiguous
    float s = 0.f, s2 = 0.f;
    for (int i = tid; i < 8192; i += 1024) {
      fltx4 v = ((const fltx4*)base)[i];
      s  += v[0] + v[1] + v[2] + v[3];
      s2 += v[0]*v[0] + v[1]*v[1] + v[2]*v[2] + v[3]*v[3];
    }
    for (int off = 1; off < 64; off <<= 1) {
      s  += __shfl_xor(s, off);
      s2 += __shfl_xor(s2, off);
    }
    __shared__ float red[32];
    int w = tid >> 6;                            // 16 waves
    if ((tid & 63) == 0) { red[w] = s; red[16 + w] = s2; }
    __syncthreads();
    if (tid < 16) {
      s  = red[tid];
      s2 = red[16 + tid];
      for (int off = 1; off < 16; off <<= 1) {
        s  += __shfl_xor(s, off);
        s2 += __shfl_xor(s2, off);
      }
      if (tid == 0) {
        float mean = s * (1.f / 32768.f);
        float var  = s2 * (1.f / 32768.f) - mean * mean;
        stats[bid * 2]     = mean;
        stats[bid * 2 + 1] = rsqrtf(var + 1e-5f);
      }
    }
    return;
  }
  const int blk = bid - 256;
  if (blk < 4) {
    const float* s = (blk < 2 ? wkv + 65536 : wout) + (blk & 1) * 32768;
    u16* d = w16 + (blk >> 1) * 65536 + (blk & 1) * 32768;
    for (int i = tid * 4; i < 32768; i += 4096) {
      fltx4 v = *(const fltx4*)(s + i);
      u32x2 o;
      o[0] = (u32)f2bf(v[0]) | ((u32)f2bf(v[1]) << 16);
      o[1] = (u32)f2bf(v[2]) | ((u32)f2bf(v[3]) << 16);
      *(u32x2*)(d + i) = o;
    }
  } else if (tid < 256) {
    const int p = blk - 4, c = tid;
    float a0 = 0.f, a1 = 0.f, a2 = 0.f;
    for (int o = p * 64; o < p * 64 + 64; ++o) {
      float kv = wkv[o * 256 + c];
      a0 += wq[o * 3 + 0] * kv;
      a1 += wq[o * 3 + 1] * kv;
      a2 += wq[o * 3 + 2] * kv;
    }
    float* dst = wq3p + (p * 256 + c) * 4;
    dst[0] = a0 * QSCALE; dst[1] = a1 * QSCALE; dst[2] = a2 * QSCALE; dst[3] = 0.f;
  }
}

// --------------------- FUSED: groupnorm-apply + K3 + V-GEMM (normT eliminated)
#define TSTR 264
__global__ __launch_bounds__(256) void gn_fused(const float* __restrict__ x,
                                                const float* __restrict__ stats,
                                                const float* __restrict__ gamma,
                                                const float* __restrict__ beta,
                                                const float* __restrict__ wq3p,
                                                const u16* __restrict__ w16v,
                                                u16* __restrict__ Vv,
                                                float* __restrict__ K3x,
                                                float* __restrict__ K3y,
                                                float* __restrict__ K3z) {
  __shared__ u16 tile[64 * TSTR];            // ~33.8 KB, [n][c]
  __shared__ float wl4[256 * 4];             // combined wq3, 4 KB
  __shared__ float part[4][64][4];           // c-quarter partial K3, 4 KB
  const int tid = threadIdx.x;
  const int b = blockIdx.y, nb = blockIdx.x * 64;
  const int nIn = tid & 63, c4 = tid >> 6;   // c4 = wave
  const int lane = tid & 63;
  const int m = lane & 15, quad = lane >> 4;
  {
    const f32x4* wp = (const f32x4*)wq3p;
    *(f32x4*)&wl4[tid * 4] = wp[tid] + wp[256 + tid] + wp[512 + tid] + wp[768 + tid];
  }
  const float* xb = x + (long)b * (CDIM * NPIX);
  // ---- phase 1: normalize 64 c-rows (this wave's quarter) for column nIn
  #pragma unroll
  for (int p8 = 0; p8 < 8; ++p8) {
    U8 pk;
    #pragma unroll
    for (int e = 0; e < 8; ++e) {
      int c = c4 * 64 + p8 * 8 + e;
      int g = c >> 3;
      float mean = stats[(b * 32 + g) * 2];
      float rstd = stats[(b * 32 + g) * 2 + 1];
      float v = xb[(long)c * NPIX + nb + nIn];
      pk.u[e] = f2bf((v - mean) * rstd * gamma[c] + beta[c]);
    }
    *(bf16x8*)&tile[nIn * TSTR + c4 * 64 + p8 * 8] = pk.v;
  }
  __syncthreads();
  // ---- phase 2: K3 partial, vectorized row reads
  {
    float a0 = 0.f, a1 = 0.f, a2 = 0.f;
    #pragma unroll
    for (int p8 = 0; p8 < 8; ++p8) {
      U8 v; v.v = *(const bf16x8*)&tile[nIn * TSTR + c4 * 64 + p8 * 8];
      #pragma unroll
      for (int e = 0; e < 8; ++e) {
        int c = c4 * 64 + p8 * 8 + e;
        float f = bf2f(v.u[e]);
        const f32x4 wv = *(const f32x4*)&wl4[c * 4];
        a0 += f * wv[0]; a1 += f * wv[1]; a2 += f * wv[2];
      }
    }
    part[c4][nIn][0] = a0; part[c4][nIn][1] = a1; part[c4][nIn][2] = a2;
  }
  __syncthreads();
  if (c4 == 0) {
    float s0 = part[0][nIn][0] + part[1][nIn][0] + part[2][nIn][0] + part[3][nIn][0];
    float s1 = part[0][nIn][1] + part[1][nIn][1] + part[2][nIn][1] + part[3][nIn][1];
    float s2 = part[0][nIn][2] + part[1][nIn][2] + part[2][nIn][2] + part[3][nIn][2];
    long idx = (long)b * NPIX + nb + nIn;
    K3x[idx] = s0; K3y[idx] = s1; K3z[idx] = s2;
  }
  // ---- phase 3: V-GEMM. wave c4 owns o-range [c4*64, c4*64+64).
  f32x4 acc[4][4] = {};
  #pragma unroll
  for (int ks = 0; ks < 8; ++ks) {
    const int kb = ks * 32;
    bf16x8 av[4], bv[4];
    #pragma unroll
    for (int i = 0; i < 4; ++i)
      av[i] = *(const bf16x8*)&w16v[(c4 * 64 + i * 16 + m) * 256 + kb + quad * 8];
    #pragma unroll
    for (int i = 0; i < 4; ++i)
      bv[i] = *(const bf16x8*)&tile[(i * 16 + m) * TSTR + kb + quad * 8];
    #pragma unroll
    for (int mi = 0; mi < 4; ++mi)
      #pragma unroll
      for (int ni = 0; ni < 4; ++ni)
        acc[mi][ni] = __builtin_amdgcn_mfma_f32_16x16x32_bf16(av[mi], bv[ni], acc[mi][ni], 0, 0, 0);
  }
  u16* Vb = Vv + (long)b * (CDIM * NPIX);
  #pragma unroll
  for (int mi = 0; mi < 4; ++mi)
    #pragma unroll
    for (int r = 0; r < 4; ++r) {
      int o = c4 * 64 + mi * 16 + quad * 4 + r;
      #pragma unroll
      for (int ni = 0; ni < 4; ++ni)
        Vb[(long)o * NPIX + nb + ni * 16 + m] = f2bf(acc[mi][ni][r]);
    }
}

// ----------------------------------- final GEMM: merge-free K=512 dual accumulation
// out[o][n] = inv[n] * (sum_c wout[o][c]*Op0[n][c] + sum_c wout[o][c]*Op1[n][c])
//           + bias[o] + resid[o][n]
// inv applied in EPILOGUE (constant across c) -> B staging is a pure copy via
// global_load_lds with XOR-chunk swizzle (attn-proven pattern): rows are 8-aligned
// per 1KB chunk so global slot = (l&7)^(l>>3); ds_read chunk = (s*4+quad)^(m&7).
// 64x128 tile, LDS 24.5 KB, 4 blocks/CU, acc[2][4]=32 regs (no spill regime).
__global__ __launch_bounds__(256, 4) void gemm_out(
    const u16* __restrict__ Ap, const u16* __restrict__ B0,
    const u16* __restrict__ B1, const float* __restrict__ ls,
    float* __restrict__ out, const float* __restrict__ bias,
    const float* __restrict__ resid) {
  __shared__ u16 Als[64 * 64];               // 8 KB, linear, chunk-swizzled
  __shared__ u16 Bls[128 * 64];              // 16 KB
  __shared__ float invB[128];
  const int tid = threadIdx.x;
  const int lane = tid & 63;
  const int w = tid >> 6;                    // wave 0..3
  const int m = lane & 15, quad = lane >> 4;
  const int wm = w & 1, wn = w >> 1;
  const int m0 = blockIdx.x * 64, n0 = blockIdx.y * 128;
  const int bz = blockIdx.z;
  const long S = (long)NPIX * CDIM;

  if (tid < 128) {
    long n = (long)bz * 4096 + n0 + tid;
    invB[tid] = 1.f / (ls[n] + ls[32768 + n]);
  }
  __syncthreads();

  // per-lane swizzled global offsets (without kb): slot = (l&7) ^ (l>>3 = row&7)
  const int slotOff = ((lane & 7) ^ (lane >> 3)) * 8;
  int srcA[2], srcB[4];
  #pragma unroll
  for (int it = 0; it < 2; ++it) {
    int row = (w * 2 + it) * 8 + (lane >> 3);          // 0..63
    srcA[it] = (m0 + row) * CDIM + slotOff;
  }
  #pragma unroll
  for (int it = 0; it < 4; ++it) {
    int row = (w * 4 + it) * 8 + (lane >> 3);          // 0..127
    srcB[it] = (n0 + row) * CDIM + slotOff;
  }

  f32x4 acc[2][4] = {};

  #pragma unroll
  for (int ks = 0; ks < 8; ++ks) {
    const int kb = (ks & 3) * 64;
    const u16* Bsrc = (ks < 4 ? B0 : B1) + S * bz;
    if (ks) __syncthreads();                 // previous tile reads done
    #pragma unroll
    for (int it = 0; it < 2; ++it)
      llds16(Als + (w * 2 + it) * 512, Ap + srcA[it] + kb);
    #pragma unroll
    for (int it = 0; it < 4; ++it)
      llds16(Bls + (w * 4 + it) * 512, Bsrc + (long)srcB[it] + kb);
    __syncthreads();                          // own DMA drained (vmcnt) + all waves
    #pragma unroll
    for (int s = 0; s < 2; ++s) {
      const int chunk = ((s * 4 + quad) ^ (m & 7)) * 8;
      bf16x8 av[2], bv[4];
      #pragma unroll
      for (int i = 0; i < 2; ++i)
        av[i] = *(const bf16x8*)&Als[(wm * 32 + i * 16 + m) * 64 + chunk];
      #pragma unroll
      for (int i = 0; i < 4; ++i)
        bv[i] = *(const bf16x8*)&Bls[(wn * 64 + i * 16 + m) * 64 + chunk];
      #pragma unroll
      for (int mi = 0; mi < 2; ++mi)
        #pragma unroll
        for (int ni = 0; ni < 4; ++ni)
          acc[mi][ni] = __builtin_amdgcn_mfma_f32_16x16x32_bf16(av[mi], bv[ni], acc[mi][ni], 0, 0, 0);
    }
  }

  const int row0 = m0 + wm * 32;
  const int col0 = n0 + wn * 64 + m;
  float* ob = out + S * bz;
  const float* res = resid + S * bz;
  float iv[4];
  #pragma unroll
  for (int ni = 0; ni < 4; ++ni)
    iv[ni] = invB[wn * 64 + ni * 16 + m];
  #pragma unroll
  for (int mi = 0; mi < 2; ++mi)
    #pragma unroll
    for (int r = 0; r < 4; ++r) {
      int row = row0 + mi * 16 + quad * 4 + r;
      float bs = bias[row];
      #pragma unroll
      for (int ni = 0; ni < 4; ++ni) {
        long off = (long)row * NPIX + col0 + ni * 16;
        ob[off] = acc[mi][ni][r] * iv[ni] + bs + res[off];
      }
    }
}

// ------------------------------------------------------------------- flash attention
// VERBATIM R9 structure (banked 97.7us): KVBLK=64, 2-way split-K, 4 waves x 32 q,
// rolled pipeline, FEXP2, LDS 64KB dbuf, 2 blocks/CU. (R10's setprio: -2us, reverted.)
#define MFMA16(a, bfr, c) __builtin_amdgcn_mfma_f32_16x16x32_bf16(a, bfr, c, 0, 0, 0)

#define P_LOAD(ks, JB)                                                      \
  {                                                                         \
    const int jo_ = (JB) + (ks) * 32 + quad * 8;                            \
    kx0 = *(const fltx4*)(Kx + jo_); kx1 = *(const fltx4*)(Kx + jo_ + 4);   \
    ky0 = *(const fltx4*)(Ky + jo_); ky1 = *(const fltx4*)(Ky + jo_ + 4);   \
    kz0 = *(const fltx4*)(Kz + jo_); kz1 = *(const fltx4*)(Kz + jo_ + 4);   \
  }

#define P_EXP(PB, ks)                                                       \
  {                                                                         \
    f32x2 xc_[4] = {LO2(kx0), HI2(kx0), LO2(kx1), HI2(kx1)};                \
    f32x2 yc_[4] = {LO2(ky0), HI2(ky0), LO2(ky1), HI2(ky1)};                \
    f32x2 zc_[4] = {LO2(kz0), HI2(kz0), LO2(kz1), HI2(kz1)};                \
    _Pragma("unroll")                                                       \
    for (int qm_ = 0; qm_ < 2; ++qm_) {                                     \
      _Pragma("unroll")                                                     \
      for (int c2_ = 0; c2_ < 4; ++c2_) {                                   \
        f32x2 s_ = xc_[c2_] * y2[qm_][0] + yc_[c2_] * y2[qm_][1]            \
                 + zc_[c2_] * y2[qm_][2];                                   \
        float p0_ = FEXP2(s_[0]);                                           \
        float p1_ = FEXP2(s_[1]);                                           \
        u32 r0_ = __builtin_bit_cast(u32, p0_) + 0x8000u;                   \
        u32 r1_ = __builtin_bit_cast(u32, p1_) + 0x8000u;                   \
        PB[qm_][ks].w[c2_] = (r0_ >> 16) | (r1_ & 0xffff0000u);             \
        f32x2 pv_; pv_[0] = p0_; pv_[1] = p1_;                              \
        lsv[qm_] += pv_;                                                    \
      }                                                                     \
    }                                                                       \
  }

#define PV_GROUP(PB, CT0)                                                   \
  _Pragma("unroll")                                                         \
  for (int ct_ = (CT0); ct_ < (CT0) + 4; ++ct_) {                           \
    int c_ = ct_ * 16 + m;                                                  \
    bf16x8 a0_ = *(const bf16x8*)&Vb[c_ * 64 + (((quad)     ^ (c_ & 7)) << 3)]; \
    bf16x8 a1_ = *(const bf16x8*)&Vb[c_ * 64 + (((4 + quad) ^ (c_ & 7)) << 3)]; \
    acc[0][ct_] = MFMA16(a0_, PB[0][0].v, acc[0][ct_]);                     \
    acc[1][ct_] = MFMA16(a0_, PB[1][0].v, acc[1][ct_]);                     \
    acc[0][ct_] = MFMA16(a1_, PB[0][1].v, acc[0][ct_]);                     \
    acc[1][ct_] = MFMA16(a1_, PB[1][1].v, acc[1][ct_]);                     \
  }

__global__ __launch_bounds__(256, 2) void attn_kernel(
    const float* __restrict__ quary,
    const float* __restrict__ K3x, const float* __restrict__ K3y,
    const float* __restrict__ K3z,
    const u16* __restrict__ V, u16* __restrict__ Op0, u16* __restrict__ Op1,
    float* __restrict__ lsum) {
  __shared__ u16 VLS[2][256 * 64];   // 2 x 32 KB; row c (256) x 64 keys, chunk ^= (c&7)
  const int lane = threadIdx.x & 63, w = threadIdx.x >> 6;   // w in [0,4)
  const int m = lane & 15, quad = lane >> 4;
  const int b = blockIdx.z, half = blockIdx.y;
  const int qb = blockIdx.x * 128 + w * 32;                  // 32 q per wave

  f32x2 y2[2][3];
  #pragma unroll
  for (int qm = 0; qm < 2; ++qm) {
    int n = qb + qm * 16 + m;
    float q0 = quary[b * 12288 + n];
    float q1 = quary[b * 12288 + 4096 + n];
    float q2 = quary[b * 12288 + 8192 + n];
    y2[qm][0][0] = q0; y2[qm][0][1] = q0;
    y2[qm][1][0] = q1; y2[qm][1][1] = q1;
    y2[qm][2][0] = q2; y2[qm][2][1] = q2;
  }

  const float* Kx = K3x + (long)b * NPIX + half * 2048;
  const float* Ky = K3y + (long)b * NPIX + half * 2048;
  const float* Kz = K3z + (long)b * NPIX + half * 2048;
  const u16* VG = V + (long)b * CDIM * NPIX + half * 2048;

  int srcV[8];
  #pragma unroll
  for (int i = 0; i < 8; ++i) {
    int c = (w * 8 + i) * 8 + (lane >> 3);
    srcV[i] = c * NPIX + (((lane & 7) ^ (c & 7)) << 3);
  }

  f32x2 lsv[2] = {};
  f32x4 acc[2][16] = {};
  U8 pbA[2][2], pbB[2][2];
  fltx4 kx0, kx1, ky0, ky1, kz0, kz1;

  #pragma unroll
  for (int i = 0; i < 8; ++i)
    llds16(VLS[0] + (w * 8 + i) * 512, VG + srcV[i]);

  P_LOAD(0, 0); P_EXP(pbA, 0);
  P_LOAD(1, 0); P_EXP(pbA, 1);

  for (int kt = 0; kt < 31; ++kt) {
    __syncthreads();
    #pragma unroll
    for (int i = 0; i < 8; ++i)
      llds16(VLS[(kt + 1) & 1] + (w * 8 + i) * 512, VG + srcV[i] + (kt + 1) * 64);
    const u16* Vb = VLS[kt & 1];
    const int JB = (kt + 1) * 64;

    P_LOAD(0, JB);
    PV_GROUP(pbA, 0);
    PV_GROUP(pbA, 4);
    P_EXP(pbB, 0);
    P_LOAD(1, JB);
    PV_GROUP(pbA, 8);
    PV_GROUP(pbA, 12);
    P_EXP(pbB, 1);

    pbA[0][0] = pbB[0][0]; pbA[0][1] = pbB[0][1];
    pbA[1][0] = pbB[1][0]; pbA[1][1] = pbB[1][1];
  }
  {
    __syncthreads();
    const u16* Vb = VLS[1];
    PV_GROUP(pbA, 0);
    PV_GROUP(pbA, 4);
    PV_GROUP(pbA, 8);
    PV_GROUP(pbA, 12);
  }

  u16* OpB = (half ? Op1 : Op0);
  #pragma unroll
  for (int qm = 0; qm < 2; ++qm) {
    int n = qb + qm * 16 + m;
    u16* row = OpB + ((long)b * NPIX + n) * CDIM + quad * 4;
    #pragma unroll
    for (int ct = 0; ct < 16; ++ct) {
      u32x2 o;
      o[0] = (u32)f2bf(acc[qm][ct][0]) | ((u32)f2bf(acc[qm][ct][1]) << 16);
      o[1] = (u32)f2bf(acc[qm][ct][2]) | ((u32)f2bf(acc[qm][ct][3]) << 16);
      *(u32x2*)(row + ct * 16) = o;
    }
    float ls = lsv[qm][0] + lsv[qm][1];
    ls += __shfl_xor(ls, 16);
    ls += __shfl_xor(ls, 32);
    if (lane < 16)
      lsum[(long)half * 32768 + (long)b * NPIX + n] = ls;
  }
}

// ----------------------------------------------------------------------- launch
extern "C" void kernel_launch(void* const* d_in, const int* in_sizes, int n_in,
                              void* d_out, int out_size, void* d_ws, size_t ws_size,
                              hipStream_t stream) {
  (void)in_sizes; (void)n_in; (void)out_size; (void)ws_size;
  const float* input = (const float*)d_in[0];   // (8,256,64,64)
  const float* quary = (const float*)d_in[1];   // (8,3,64,64)
  const float* gnw   = (const float*)d_in[2];   // (256)
  const float* gnb   = (const float*)d_in[3];   // (256)
  const float* wq    = (const float*)d_in[4];   // (256,3)
  const float* wkv   = (const float*)d_in[5];   // (512,256)
  const float* wout  = (const float*)d_in[6];   // (256,256)
  const float* bout  = (const float*)d_in[7];   // (256)
  float* out = (float*)d_out;

  char* ws = (char*)d_ws;
  float* stats = (float*)ws;                              // 4 KB    @0
  float* wq3p  = (float*)(ws + 4096);                     // 16 KB
  float* lsum  = (float*)(ws + 20480);                    // 256 KB (2 x 32768 f32)
  float* K3x   = (float*)(ws + 282624);                   // 128 KB plane
  float* K3y   = (float*)(ws + 413696);                   // 128 KB plane
  float* K3z   = (float*)(ws + 544768);                   // 128 KB plane
  u16* w16   = (u16*)(ws + 675840);                       // 256 KB -> ends 937984
  const long base = 937984;
  u16* Vv    = (u16*)(ws + base);                         // 16 MiB (B,C,N)
  u16* Op0   = (u16*)(ws + base + 1L * 16777216);         // 16 MiB
  u16* Op1   = (u16*)(ws + base + 2L * 16777216);         // 16 MiB

  gn_stats_prep<<<264, 1024, 0, stream>>>(input, wkv, wout, wq, stats, w16, wq3p);
  gn_fused<<<dim3(64, 8), 256, 0, stream>>>(input, stats, gnw, gnb, wq3p,
                                            w16, Vv, K3x, K3y, K3z);
  attn_kernel<<<dim3(32, 2, 8), 256, 0, stream>>>(quary, K3x, K3y, K3z, Vv, Op0, Op1, lsum);
  gemm_out<<<dim3(4, 32, 8), 256, 0, stream>>>(
      w16 + 65536, Op0, Op1, lsum, out, bout, input);
}